// Round 6
// baseline (71.749 us; speedup 1.0000x reference)
//
#include <hip/hip_runtime.h>

#define GRID 1024          // pair-kernel blocks
#define PBLK 512           // pair-kernel threads (8 waves)
#define RT   16            // a-values per thread: PBLK*RT = 8192 = N
#define BCH  8             // b-columns prefetched per block chunk

#define LOG2E 1.4426950408889634f
#define LN2   0.6931471805599453
#define BIGF  1.0e30f      // a-side mask bias -> s clamps to 64, e=2^-64: no-op

__device__ __forceinline__ float fast_log2(float x) {
#if __has_builtin(__builtin_amdgcn_logf)
    return __builtin_amdgcn_logf(x);       // v_log_f32
#else
    return log2f(x);
#endif
}
__device__ __forceinline__ float fast_ldexp(float x, int n) {
#if __has_builtin(__builtin_amdgcn_ldexpf)
    return __builtin_amdgcn_ldexpf(x, n);  // v_ldexp_f32, full-rate VALU
#else
    return ldexpf(x, n);
#endif
}

// 2^-s for s in [0,64], pure full-rate VALU (no v_exp):
//   s = w + f, w=floor(s), f in [0,1);  2^-f by deg-5 Taylor (|rel err|<=1.5e-4);
//   scale by 2^-w via v_ldexp (cvt_i32 of -w: neg folds as src modifier).
__device__ __forceinline__ float exp2n_valu(float s) {
    const float w = floorf(s);
    const float f = s - w;
    const int   n = (int)(-w);             // w in [0,64] -> no UB
    float q = -1.3333558e-3f;              // ln^5(2)/120 (sign-folded)
    q = fmaf(q, f,  9.6181291e-3f);        // ln^4(2)/24
    q = fmaf(q, f, -5.5504109e-2f);        // ln^3(2)/6
    q = fmaf(q, f,  2.4022651e-1f);        // ln^2(2)/2
    q = fmaf(q, f, -6.9314718e-1f);        // ln(2)
    q = fmaf(q, f,  1.0f);
    return fast_ldexp(q, n);
}

// ---------------------------------------------------------------------------
//   sum_{a,b} [ty[a]==1][ty[b]==0] * softplus(v[b]-v[a])
// Log2 domain: softplus(x)/ln2 = max(x2,0) + log2(1 + 2^-|x2|), x2 = x*log2e.
// Per b-column each thread multiplies its 16 factors (1+2^-|x2|) into p
// (each factor in (1,2], p <= 2^16) and takes ONE v_log — the only trans op.
// 2^-|x2| is computed by the VALU-only exp2n_valu above (v_exp_f32 measured
// ~1 lane/cy/SIMD in r2-r5 — it was the bottleneck, not VALU issue).
// a-side mask free: masked entries hold pa=1e30 -> max term 0, factor 1.
// b-columns with ty==1 skipped wave-uniformly.
// Deterministic: partials[bid] written unconditionally, no atomics, no init.
// ---------------------------------------------------------------------------
__global__ __launch_bounds__(PBLK) void pair_kernel(
        const float* __restrict__ v,
        const int* __restrict__ ty,
        float* __restrict__ partials,
        int N) {
    const int tid = threadIdx.x;

    // Register-resident a-slice (float4/int4 coalesced), bias-masked.
    float pa[RT];
    const float4* v4 = (const float4*)v;
    const int4*   t4 = (const int4*)ty;
    #pragma unroll
    for (int j = 0; j < RT / 4; ++j) {
        const int q = j * PBLK + tid;      // float4 index
        const float4 vv = v4[q];
        const int4   tt = t4[q];
        pa[4*j+0] = (tt.x == 1) ? vv.x * LOG2E : BIGF;
        pa[4*j+1] = (tt.y == 1) ? vv.y * LOG2E : BIGF;
        pa[4*j+2] = (tt.z == 1) ? vv.z * LOG2E : BIGF;
        pa[4*j+3] = (tt.w == 1) ? vv.w * LOG2E : BIGF;
    }

    float accm = 0.0f;   // sum of max(x2,0) terms
    float accl = 0.0f;   // sum of log2(prod) terms

    for (int b0 = blockIdx.x; b0 < N; b0 += GRID * BCH) {
        // Prefetch this chunk's uniform b-metadata (independent loads).
        float vb[BCH];
        int   tb[BCH];
        #pragma unroll
        for (int k = 0; k < BCH; ++k) {
            const int b  = b0 + k * GRID;
            const bool ok = (b < N);
            vb[k] = ok ? v[b] * LOG2E : 0.0f;
            tb[k] = ok ? ty[b] : 1;          // 1 => skip
        }
        #pragma unroll
        for (int k = 0; k < BCH; ++k) {
            if (tb[k] != 0) continue;        // uniform -> scalar branch
            const float vbl = vb[k];
            float p = 1.0f;
            #pragma unroll
            for (int r = 0; r < RT; ++r) {
                const float x = vbl - pa[r];
                accm += fmaxf(x, 0.0f);
                const float s = fminf(fabsf(x), 64.0f);
                const float e = exp2n_valu(s);
                p = fmaf(p, e, p);                      // p *= (1 + e)
            }
            accl += fast_log2(p);
        }
    }

    float acc = accm + accl;

    // wave reduce, then cross-wave via LDS
    for (int off = 32; off > 0; off >>= 1)
        acc += __shfl_down(acc, off, 64);

    __shared__ float wsum[PBLK / 64];
    const int lane = tid & 63;
    const int wid  = tid >> 6;
    if (lane == 0) wsum[wid] = acc;
    __syncthreads();
    if (tid == 0) {
        float s = 0.0f;
        #pragma unroll
        for (int wdx = 0; wdx < PBLK / 64; ++wdx) s += wsum[wdx];
        partials[blockIdx.x] = s;            // unconditional
    }
}

// ---------------------------------------------------------------------------
// Single block: total = sum(partials); P,Q counted straight from ty;
// out = ln2 * total / (P*Q).
// ---------------------------------------------------------------------------
__global__ __launch_bounds__(PBLK) void finalize_kernel(
        const float* __restrict__ partials, int nparts,
        const int* __restrict__ ty, int N,
        float* __restrict__ out) {
    const int tid = threadIdx.x;

    double s = 0.0;
    for (int k = tid; k < nparts; k += PBLK) s += (double)partials[k];

    int cp = 0, cn = 0;
    for (int k = tid; k < N; k += PBLK) {
        const int t = ty[k];
        cp += (t == 1);
        cn += (t == 0);
    }

    __shared__ double sd[PBLK];
    __shared__ int    sp_[PBLK];
    __shared__ int    sn_[PBLK];
    sd[tid] = s; sp_[tid] = cp; sn_[tid] = cn;
    __syncthreads();
    for (int off = PBLK / 2; off > 0; off >>= 1) {
        if (tid < off) {
            sd[tid]  += sd[tid + off];
            sp_[tid] += sp_[tid + off];
            sn_[tid] += sn_[tid + off];
        }
        __syncthreads();
    }
    if (tid == 0) {
        const double denom = (double)sp_[0] * (double)sn_[0];
        out[0] = (float)(sd[0] * LN2 / denom);
    }
}

extern "C" void kernel_launch(void* const* d_in, const int* in_sizes, int n_in,
                              void* d_out, int out_size, void* d_ws, size_t ws_size,
                              hipStream_t stream) {
    const float* v  = (const float*)d_in[0];   // pred_y fp32, N = n*K = 8192
    const int*   ty = (const int*)d_in[1];     // true_y int32 {0,1}
    float* out = (float*)d_out;
    const int N = in_sizes[0];

    float* partials = (float*)d_ws;            // GRID floats, fully overwritten

    pair_kernel<<<GRID, PBLK, 0, stream>>>(v, ty, partials, N);
    finalize_kernel<<<1, PBLK, 0, stream>>>(partials, GRID, ty, N, out);
}

// Round 7
// 67.935 us; speedup vs baseline: 1.0561x; 1.0561x over previous
//
#include <hip/hip_runtime.h>

#define CBLK 256
#define GRID 1024          // pair-kernel blocks
#define PBLK 512           // pair-kernel threads (8 waves)
#define RT   9             // pos per thread per chunk: 512*9 = 4608 >= P (mean+11 sigma)

#define LOG2E 1.4426950408889634f
#define LN2   0.6931471805599453
#define BIGF  1.0e30f      // mask bias: x=-1e30 -> max term 0, exp2(-|x|)=0, factor 1

__device__ __forceinline__ float fast_exp2(float x) {
#if __has_builtin(__builtin_amdgcn_exp2f)
    return __builtin_amdgcn_exp2f(x);      // v_exp_f32
#else
    return exp2f(x);
#endif
}
__device__ __forceinline__ float fast_log2(float x) {
#if __has_builtin(__builtin_amdgcn_logf)
    return __builtin_amdgcn_logf(x);       // v_log_f32
#else
    return log2f(x);
#endif
}

// ---------------------------------------------------------------------------
// Pass 1: compact pred*log2(e) into dense vpos[] (ty==1) / vneg[] (ty==0).
// Ballot-based wave compaction, one atomic per wave per list.
// cnt[0]=P, cnt[1]=Q (zeroed by the 8-byte memset node).
// ---------------------------------------------------------------------------
__global__ void compact_kernel(const float* __restrict__ v,
                               const int* __restrict__ ty,
                               int* __restrict__ cnt,
                               float* __restrict__ vpos,
                               float* __restrict__ vneg,
                               int N) {
    const int i    = blockIdx.x * blockDim.x + threadIdx.x;
    const int lane = threadIdx.x & 63;

    const bool valid = (i < N);
    float val = 0.0f;
    int   t   = -1;
    if (valid) { val = v[i] * LOG2E; t = ty[i]; }

    const bool isP = valid && (t == 1);
    const bool isN = valid && (t == 0);

    const unsigned long long mp = __ballot(isP);
    const unsigned long long mn = __ballot(isN);
    const unsigned long long lt = (lane == 0) ? 0ull : (~0ull >> (64 - lane));

    int basep = 0, basen = 0;
    if (lane == 0) {
        basep = atomicAdd(&cnt[0], __popcll(mp));
        basen = atomicAdd(&cnt[1], __popcll(mn));
    }
    basep = __shfl(basep, 0, 64);
    basen = __shfl(basen, 0, 64);

    if (isP) vpos[basep + __popcll(mp & lt)] = val;
    if (isN) vneg[basen + __popcll(mn & lt)] = val;
}

// ---------------------------------------------------------------------------
// Pass 2: sum over the dense P x Q pair space — NO branches, NO divergence,
// perfectly uniform work per block (the r4-r6 versions skipped ty[b]==1
// columns wave-uniformly -> Binomial(8,1/2) work per block -> ~1.5x tail).
// Thread holds RT=9 compacted pos values in registers (BIGF past P: the mask
// is free). Block bid owns dense neg columns b = bid + k*GRID (~4 each,
// +-1). Per r-iter: sub, max, add, exp2(-|x|, mods fold), fmac = 16 cy/wave;
// one v_log per column (product of 9 factors <= 2^9, no overflow).
// Deterministic: partials[bid] written unconditionally.
// ---------------------------------------------------------------------------
__global__ __launch_bounds__(PBLK) void pair_kernel(
        const int* __restrict__ cnt,
        const float* __restrict__ vpos,
        const float* __restrict__ vneg,
        float* __restrict__ partials) {
    const int P   = cnt[0];
    const int Q   = cnt[1];
    const int tid = threadIdx.x;

    float accm = 0.0f;   // sum of max(x2,0) terms
    float accl = 0.0f;   // sum of log2(prod) terms

    for (int base = 0; base < P; base += RT * PBLK) {   // 1 chunk for P<=4608
        float pa[RT];
        #pragma unroll
        for (int r = 0; r < RT; ++r) {
            const int idx = base + r * PBLK + tid;      // lane-consecutive
            pa[r] = (idx < P) ? vpos[idx] : BIGF;
        }

        for (int b = blockIdx.x; b < Q; b += GRID) {
            const float vbl = vneg[b];                  // uniform -> s_load
            float p = 1.0f;
            #pragma unroll
            for (int r = 0; r < RT; ++r) {
                const float x = vbl - pa[r];
                accm += fmaxf(x, 0.0f);
                const float e = fast_exp2(-fabsf(x));   // src mods fold
                p = fmaf(p, e, p);                      // p *= (1 + e)
            }
            accl += fast_log2(p);                       // 1 trans per 9 pairs
        }
    }

    float acc = accm + accl;

    // wave reduce, then cross-wave via LDS
    for (int off = 32; off > 0; off >>= 1)
        acc += __shfl_down(acc, off, 64);

    __shared__ float wsum[PBLK / 64];
    const int lane = tid & 63;
    const int wid  = tid >> 6;
    if (lane == 0) wsum[wid] = acc;
    __syncthreads();
    if (tid == 0) {
        float s = 0.0f;
        #pragma unroll
        for (int wdx = 0; wdx < PBLK / 64; ++wdx) s += wsum[wdx];
        partials[blockIdx.x] = s;            // unconditional
    }
}

// ---------------------------------------------------------------------------
// Pass 3: out = ln2 * sum(partials) / (P*Q), double accumulation.
// ---------------------------------------------------------------------------
__global__ __launch_bounds__(256) void finalize_kernel(
        const float* __restrict__ partials, int nparts,
        const int* __restrict__ cnt,
        float* __restrict__ out) {
    const int tid = threadIdx.x;
    double s = 0.0;
    for (int k = tid; k < nparts; k += 256) s += (double)partials[k];

    __shared__ double sd[256];
    sd[tid] = s;
    __syncthreads();
    for (int off = 128; off > 0; off >>= 1) {
        if (tid < off) sd[tid] += sd[tid + off];
        __syncthreads();
    }
    if (tid == 0) {
        const double denom = (double)cnt[0] * (double)cnt[1];
        out[0] = (float)(sd[0] * LN2 / denom);
    }
}

extern "C" void kernel_launch(void* const* d_in, const int* in_sizes, int n_in,
                              void* d_out, int out_size, void* d_ws, size_t ws_size,
                              hipStream_t stream) {
    const float* v  = (const float*)d_in[0];   // pred_y fp32, N = n*K = 8192
    const int*   ty = (const int*)d_in[1];     // true_y int32 {0,1}
    float* out = (float*)d_out;
    const int N = in_sizes[0];

    // ws layout: [cnt:2 ints][pad to 64B][vpos:N][vneg:N][partials:GRID]
    char*  ws       = (char*)d_ws;
    int*   cnt      = (int*)ws;
    float* vpos     = (float*)(ws + 64);
    float* vneg     = vpos + N;
    float* partials = vneg + N;

    hipMemsetAsync(cnt, 0, 2 * sizeof(int), stream);   // capturable memset node

    const int cblocks = (N + CBLK - 1) / CBLK;
    compact_kernel<<<cblocks, CBLK, 0, stream>>>(v, ty, cnt, vpos, vneg, N);
    pair_kernel<<<GRID, PBLK, 0, stream>>>(cnt, vpos, vneg, partials);
    finalize_kernel<<<1, 256, 0, stream>>>(partials, GRID, cnt, out);
}